// Round 2
// baseline (139.878 us; speedup 1.0000x reference)
//
#include <hip/hip_runtime.h>

// PhenoRotary3DPositionalEncoder
// x: (16, 8192, 6) fp32 in [0,1)  ->  enc: (16, 8192, 256) fp32
//
// For half-dim index k in [0,128):
//   k < 2  -> pad: (1, 1)
//   k >= 2 -> j=k-2, coord=j/21, f=j%21
//             a = x[pos*6+coord] * 20*pi * 10000^(-f/21)
//             enc[2k]   = cos(a)+sin(a) = sqrt2 * sin(a + pi/4)
//             enc[2k+1] = cos(a)-sin(a) = sqrt2 * cos(a + pi/4)
// In revolutions: r = fract(x * s_rev + 1/8), s_rev = 10 * 10000^(-f/21);
// pad (k<2) falls out with s_rev=0, coordoff=0: r=1/8 -> both outputs 1.
//
// R2 change: PERSISTENT-STYLE. The poison fill (rocclr fillBuffer) sustains
// 6.7 TB/s at 9% occupancy: few waves, each with hundreds of stores in
// flight. Our previous kernel was the inverse (65536 waves x 2 stores) and
// achieved ~2.8 TB/s. Now each thread keeps its quad slot u (table entry
// hoisted once) and loops PPT=16 consecutive positions -> 32 independent nt
// stores per thread, 16x fewer waves (4096 = 4/SIMD), store queue stays
// deep. Per-iter addresses fold to base + immediate after full unroll.

#define LOG2_10000_OVER_21 0.6327482085499738f
#define SQRT2              1.4142135623730951f
#define PPT 16   // positions per thread

typedef float v4f __attribute__((ext_vector_type(4)));

// One position's worth of work for this thread's quad pair.
#define BODY(IT)                                                              \
    {                                                                         \
        const char* xr = xb + (IT) * 24;                                      \
        float x00 = *(const float*)(xr + off00);                              \
        float x01 = *(const float*)(xr + off01);                              \
        float x10 = *(const float*)(xr + off10);                              \
        float x11 = *(const float*)(xr + off11);                              \
        float r00 = __builtin_amdgcn_fractf(fmaf(x00, s00, 0.125f));          \
        float r01 = __builtin_amdgcn_fractf(fmaf(x01, s01, 0.125f));          \
        float r10 = __builtin_amdgcn_fractf(fmaf(x10, s10, 0.125f));          \
        float r11 = __builtin_amdgcn_fractf(fmaf(x11, s11, 0.125f));          \
        v4f o0, o1;                                                           \
        o0.x = SQRT2 * __builtin_amdgcn_sinf(r00);                            \
        o0.y = SQRT2 * __builtin_amdgcn_cosf(r00);                            \
        o0.z = SQRT2 * __builtin_amdgcn_sinf(r01);                            \
        o0.w = SQRT2 * __builtin_amdgcn_cosf(r01);                            \
        o1.x = SQRT2 * __builtin_amdgcn_sinf(r10);                            \
        o1.y = SQRT2 * __builtin_amdgcn_cosf(r10);                            \
        o1.z = SQRT2 * __builtin_amdgcn_sinf(r11);                            \
        o1.w = SQRT2 * __builtin_amdgcn_cosf(r11);                            \
        __builtin_nontemporal_store(o0, ob + (IT) * 64);                      \
        __builtin_nontemporal_store(o1, ob + (IT) * 64 + 32);                 \
    }

__global__ __launch_bounds__(256) void pheno_rotary_pe_kernel(
        const float* __restrict__ x,
        v4f* __restrict__ out, int npos) {
    __shared__ float2 tbl[128];   // {s_rev, coord*4 as int bits}

    int tid = threadIdx.x;
    if (tid < 128) {
        float s = 0.0f;
        int   c4 = 0;
        if (tid >= 2) {
            int j = tid - 2;
            int c = j / 21;                 // magic-mul at -O3
            int f = j - 21 * c;
            c4 = c * 4;                     // byte offset into x row
            s = 10.0f * __builtin_amdgcn_exp2f(-LOG2_10000_OVER_21 * (float)f);
        }
        tbl[tid] = make_float2(s, __int_as_float(c4));
    }
    __syncthreads();

    int idx  = blockIdx.x * 256 + tid;
    int u    = idx & 31;            // quad slot 0..31 (second quad = u+32)
    int base = (idx >> 5) * PPT;    // first position this thread handles

    // quad u covers half-dims 2u,2u+1: table entry {s0, off0, s1, off1}
    const v4f* t4 = (const v4f*)tbl;
    v4f e0 = t4[u];
    v4f e1 = t4[u + 32];
    float s00 = e0.x, s01 = e0.z, s10 = e1.x, s11 = e1.z;
    int off00 = __float_as_int(e0.y), off01 = __float_as_int(e0.w);
    int off10 = __float_as_int(e1.y), off11 = __float_as_int(e1.w);

    const char* xb = (const char*)x + base * 24;   // 6 floats per position
    v4f* ob = out + base * 64 + u;

    if (base + PPT <= npos) {
        // full tile: compile-time iteration count, addresses fold to
        // base + immediate, 32 independent nt stores in flight
#pragma unroll
        for (int it = 0; it < PPT; ++it) BODY(it);
    } else {
        for (int it = 0; it < PPT; ++it) {
            if (base + it >= npos) break;
            BODY(it);
        }
    }
}

extern "C" void kernel_launch(void* const* d_in, const int* in_sizes, int n_in,
                              void* d_out, int out_size, void* d_ws, size_t ws_size,
                              hipStream_t stream) {
    const float* x = (const float*)d_in[0];
    v4f* out = (v4f*)d_out;

    int npos     = in_sizes[0] / 6;              // 16 * 8192 = 131072
    int groups   = (npos + PPT - 1) / PPT;       // 8192 position-groups
    int nthreads = groups * 32;                  // 32 threads per group
    int block    = 256;
    int grid     = (nthreads + block - 1) / block;   // 1024 blocks, 4096 waves

    pheno_rotary_pe_kernel<<<grid, block, 0, stream>>>(x, out, npos);
}